// Round 1
// baseline (447.147 us; speedup 1.0000x reference)
//
#include <hip/hip_runtime.h>
#include <hip/hip_bf16.h>
#include <stdint.h>

#define NQ 128
#define NLVL 5

typedef float  floatx4 __attribute__((ext_vector_type(4)));
typedef short  short8  __attribute__((ext_vector_type(8)));

__device__ __forceinline__ uint16_t f2bf(float f) {
    uint32_t u = __builtin_bit_cast(uint32_t, f);
    uint32_t r = u + 0x7FFFu + ((u >> 16) & 1u);   // round-to-nearest-even
    return (uint16_t)(r >> 16);
}

// ---------------------------------------------------------------- softmax ----
struct SmParams {
    const float* w[NLVL];
    uint16_t*    smT[NLVL];   // each NQ x C, row-major in o (K-contiguous rows)
    int          C[NLVL];
};

__global__ __launch_bounds__(64) void softmax_kernel(SmParams p) {
    int b   = blockIdx.x;      // 5*128 blocks
    int lvl = b >> 7;
    int o   = b & 127;
    int C   = p.C[lvl];
    const float* w = p.w[lvl];
    int lane = threadIdx.x;    // 64
    float ev[8];
    int nIter = C >> 6;        // C/64 : 1,2,4,8,8
    float mx = -1e30f;
    for (int it = 0; it < nIter; ++it) {
        float z = 10.0f * w[(size_t)(it * 64 + lane) * NQ + o];
        ev[it] = z;
        mx = fmaxf(mx, z);
    }
    #pragma unroll
    for (int s = 32; s; s >>= 1) mx = fmaxf(mx, __shfl_xor(mx, s));
    float sum = 0.f;
    for (int it = 0; it < nIter; ++it) { ev[it] = expf(ev[it] - mx); sum += ev[it]; }
    #pragma unroll
    for (int s = 32; s; s >>= 1) sum += __shfl_xor(sum, s);
    float inv = 1.0f / sum;
    uint16_t* dst = p.smT[lvl] + (size_t)o * C;
    for (int it = 0; it < nIter; ++it) dst[it * 64 + lane] = f2bf(ev[it] * inv);
}

// ------------------------------------------------------------------- quad ----
struct QuadParams {
    const float*    x[NLVL];
    const uint16_t* smT[NLVL];
    float*          quad;          // (5*8*128) entries, padded stride 16 floats
    int             C[NLVL];
    int             HW[NLVL];
    int             blk_base[NLVL];
};

__global__ __launch_bounds__(256) void quad_kernel(QuadParams p) {
    // LDS tiles: A-tile 64h x 32c (bf16, row stride 40 shorts = 80B, 16B aligned)
    //            B-tile 128o x 32c (same stride)
    __shared__ __align__(16) short At[64 * 40];
    __shared__ __align__(16) short Bt[128 * 40];

    int bid = blockIdx.x;
    int lvl = 0;
    #pragma unroll
    for (int l = 1; l < NLVL; ++l) if (bid >= p.blk_base[l]) lvl = l;
    int rel = bid - p.blk_base[lvl];
    int n   = rel & 7;
    int ht  = rel >> 3;
    int C   = p.C[lvl];
    int HW  = p.HW[lvl];
    int h0  = ht * 64;

    const float*    xb  = p.x[lvl] + (size_t)n * C * HW + h0;
    const uint16_t* smT = p.smT[lvl];

    int t    = threadIdx.x;
    int wave = t >> 6;
    int lane = t & 63;
    int m    = lane & 15;     // output-col lane / frag row
    int kg   = lane >> 4;     // k-group (8 contiguous k each)

    floatx4 acc[4][2];
    floatx4 zero = {0.f, 0.f, 0.f, 0.f};
    #pragma unroll
    for (int i = 0; i < 4; ++i)
        #pragma unroll
        for (int j = 0; j < 2; ++j) acc[i][j] = zero;

    // A staging mapping: thread t -> c pair (2*(t&15), +1), h quad 4*(t>>4)
    int c_l = (t & 15) * 2;
    int h_l = (t >> 4) * 4;

    for (int c0 = 0; c0 < C; c0 += 32) {
        // ---- stage A: 32c x 64h fp32 -> bf16 transposed to At[h][c]
        const float* s1 = xb + (size_t)(c0 + c_l) * HW + h_l;
        float4 a4 = *(const float4*)s1;
        float4 b4 = *(const float4*)(s1 + HW);
        #pragma unroll
        for (int j = 0; j < 4; ++j) {
            uint32_t pk = (uint32_t)f2bf(((const float*)&a4)[j]) |
                          ((uint32_t)f2bf(((const float*)&b4)[j]) << 16);
            *(uint32_t*)&At[(h_l + j) * 40 + c_l] = pk;
        }
        // ---- stage B: 128o x 32c bf16 (rows of smT), 16B per slot, 512 slots
        #pragma unroll
        for (int it = 0; it < 2; ++it) {
            int idx  = it * 256 + t;
            int o    = idx >> 2;
            int part = idx & 3;
            uint4 v = *(const uint4*)(smT + (size_t)o * C + c0 + part * 8);
            *(uint4*)&Bt[o * 40 + part * 8] = v;
        }
        __syncthreads();

        short8 af[4];
        #pragma unroll
        for (int mt = 0; mt < 4; ++mt)
            af[mt] = *(const short8*)&At[(mt * 16 + m) * 40 + kg * 8];
        short8 bfr[2];
        #pragma unroll
        for (int ot = 0; ot < 2; ++ot)
            bfr[ot] = *(const short8*)&Bt[((wave * 2 + ot) * 16 + m) * 40 + kg * 8];
        #pragma unroll
        for (int mt = 0; mt < 4; ++mt)
            #pragma unroll
            for (int ot = 0; ot < 2; ++ot)
                acc[mt][ot] = __builtin_amdgcn_mfma_f32_16x16x32_bf16(
                    af[mt], bfr[ot], acc[mt][ot], 0, 0, 0);
        __syncthreads();
    }

    // ---- epilogue: sum P^2 over the 64 h rows, one atomic per (wave,ot,o)
    float* qbase = p.quad + (size_t)(lvl * 8 + n) * 128 * 16;
    #pragma unroll
    for (int ot = 0; ot < 2; ++ot) {
        float part = 0.f;
        #pragma unroll
        for (int mt = 0; mt < 4; ++mt)
            #pragma unroll
            for (int r = 0; r < 4; ++r) {
                float v = acc[mt][ot][r];
                part = fmaf(v, v, part);
            }
        part += __shfl_xor(part, 16);
        part += __shfl_xor(part, 32);
        if (lane < 16) {
            int o = (wave * 2 + ot) * 16 + lane;
            atomicAdd(qbase + (size_t)o * 16, part);
        }
    }
}

// ------------------------------------------------------------------- head ----
__device__ __forceinline__ float block_sum512(float v, float* red8, int t) {
    #pragma unroll
    for (int s = 32; s; s >>= 1) v += __shfl_xor(v, s);
    __syncthreads();                       // protect red8 across reuses
    if ((t & 63) == 0) red8[t >> 6] = v;
    __syncthreads();
    float tot = 0.f;
    #pragma unroll
    for (int i = 0; i < 8; ++i) tot += red8[i];
    return tot;
}

__global__ __launch_bounds__(512) void head_kernel(
    const float* __restrict__ quad,
    const float* __restrict__ fc1_w, const float* __restrict__ fc1_b,
    const float* __restrict__ fc2_w, const float* __restrict__ fc2_b,
    const float* __restrict__ fc3_w, const float* __restrict__ fc3_b,
    float* __restrict__ out) {
    __shared__ float feat[640];
    __shared__ float hbuf[512];
    __shared__ float red8[8];
    __shared__ float stats[10];
    int n = blockIdx.x;
    int t = threadIdx.x;

    for (int idx = t; idx < 640; idx += 512) {
        int lvl = idx >> 7, o = idx & 127;
        feat[idx] = quad[((size_t)(lvl * 8 + n) * 128 + o) * 16];
    }
    __syncthreads();
    if (t < 5) {  // per-level norm stats (ddof=1), tiny serial loops
        float s = 0.f;
        for (int i = 0; i < 128; ++i) s += feat[t * 128 + i];
        float mean = s * (1.f / 128.f);
        float v = 0.f;
        for (int i = 0; i < 128; ++i) { float d = feat[t * 128 + i] - mean; v += d * d; }
        stats[t]     = mean;
        stats[5 + t] = sqrtf(v * (1.f / 127.f)) + 1e-8f;
    }
    __syncthreads();
    for (int idx = t; idx < 640; idx += 512) {
        int lvl = idx >> 7;
        feat[idx] = (feat[idx] - stats[lvl]) / stats[5 + lvl];
    }
    __syncthreads();

    // fc1 (640 -> 512) + norm + leaky
    float acc = fc1_b[t];
    #pragma unroll 8
    for (int i = 0; i < 640; ++i) acc = fmaf(feat[i], fc1_w[(size_t)i * 512 + t], acc);
    float mean = block_sum512(acc, red8, t) * (1.f / 512.f);
    float d    = acc - mean;
    float var  = block_sum512(d * d, red8, t) * (1.f / 511.f);
    float nv   = d / (sqrtf(var) + 1e-8f);
    __syncthreads();
    hbuf[t] = nv > 0.f ? nv : 0.01f * nv;
    __syncthreads();

    // fc2 (512 -> 512) + norm + leaky
    float acc2 = fc2_b[t];
    #pragma unroll 8
    for (int i = 0; i < 512; ++i) acc2 = fmaf(hbuf[i], fc2_w[(size_t)i * 512 + t], acc2);
    mean = block_sum512(acc2, red8, t) * (1.f / 512.f);
    d    = acc2 - mean;
    var  = block_sum512(d * d, red8, t) * (1.f / 511.f);
    nv   = d / (sqrtf(var) + 1e-8f);
    __syncthreads();
    hbuf[t] = nv > 0.f ? nv : 0.01f * nv;
    __syncthreads();

    // fc3 (512 -> 128), no norm/activation
    if (t < 128) {
        float acc3 = fc3_b[t];
        #pragma unroll 8
        for (int i = 0; i < 512; ++i) acc3 = fmaf(hbuf[i], fc3_w[(size_t)i * 128 + t], acc3);
        out[(size_t)n * 128 + t] = acc3;
    }
}

// ----------------------------------------------------------------- launch ----
extern "C" void kernel_launch(void* const* d_in, const int* in_sizes, int n_in,
                              void* d_out, int out_size, void* d_ws, size_t ws_size,
                              hipStream_t stream) {
    static const int Cs[NLVL]  = {64, 128, 256, 512, 512};
    static const int RESs[NLVL] = {256, 128, 64, 32, 16};

    // inputs interleaved: x0, w1_0, x1, w1_1, ..., x4, w1_4, fc1_w, fc1_b, ...
    const float* x[NLVL];
    const float* w[NLVL];
    for (int i = 0; i < NLVL; ++i) {
        x[i] = (const float*)d_in[2 * i];
        w[i] = (const float*)d_in[2 * i + 1];
    }
    const float* fc1_w = (const float*)d_in[10];
    const float* fc1_b = (const float*)d_in[11];
    const float* fc2_w = (const float*)d_in[12];
    const float* fc2_b = (const float*)d_in[13];
    const float* fc3_w = (const float*)d_in[14];
    const float* fc3_b = (const float*)d_in[15];

    // workspace layout: smT (bf16) then padded quad accumulator (fp32)
    uint16_t* smT_base = (uint16_t*)d_ws;
    int smOff[NLVL];
    int off = 0;
    for (int i = 0; i < NLVL; ++i) { smOff[i] = off; off += Cs[i] * NQ; }
    size_t smBytes = (size_t)off * sizeof(uint16_t);     // 376832, 16B multiple
    float* quad = (float*)((char*)d_ws + smBytes);
    size_t quadBytes = (size_t)NLVL * 8 * NQ * 16 * sizeof(float);  // 320 KB

    SmParams sp;
    for (int i = 0; i < NLVL; ++i) {
        sp.w[i]   = w[i];
        sp.smT[i] = smT_base + smOff[i];
        sp.C[i]   = Cs[i];
    }
    softmax_kernel<<<NLVL * NQ, 64, 0, stream>>>(sp);

    hipMemsetAsync(quad, 0, quadBytes, stream);

    QuadParams qp;
    int base = 0;
    for (int i = 0; i < NLVL; ++i) {
        qp.x[i]   = x[i];
        qp.smT[i] = smT_base + smOff[i];
        qp.C[i]   = Cs[i];
        qp.HW[i]  = RESs[i] * RESs[i];
        qp.blk_base[i] = base;
        base += (RESs[i] * RESs[i] / 64) * 8;
    }
    qp.quad = quad;
    quad_kernel<<<base, 256, 0, stream>>>(qp);   // base == 10912

    head_kernel<<<8, 512, 0, stream>>>(quad, fc1_w, fc1_b, fc2_w, fc2_b,
                                       fc3_w, fc3_b, (float*)d_out);
}